// Round 3
// baseline (136.023 us; speedup 1.0000x reference)
//
#include <hip/hip_runtime.h>
#include <hip/hip_fp16.h>

using half8  = __attribute__((ext_vector_type(8))) _Float16;
using f32x4  = __attribute__((ext_vector_type(4))) float;
using uint4v = __attribute__((ext_vector_type(4))) unsigned int;

#define GROUPS      3333
#define BINNER_OUT  9999
#define BATCH       256
#define ROWS        512          // 2 spectra x 256
#define PEAKS       512
#define K1          9999
#define K1P         10016        // K1 padded to mult of 32
#define NP          1024         // hidden 1000 padded
#define NOP         512          // out 500 padded

// ---- async global->LDS, 16B per lane (dest = uniform base + lane*16) ------
__device__ __forceinline__ void gl_lds16(const void* g, void* l) {
  __builtin_amdgcn_global_load_lds(
      (const __attribute__((address_space(1))) void*)g,
      (__attribute__((address_space(3))) void*)l, 16, 0, 0);
}

// ---- fused binning: per-row LDS accumulator -------------------------------
__global__ __launch_bounds__(256) void fused_bin(
    const float* __restrict__ mz1, const float* __restrict__ it1,
    const float* __restrict__ mz2, const float* __restrict__ it2,
    const float* __restrict__ Wg,  const float* __restrict__ bg,
    _Float16* __restrict__ h16) {
  __shared__ float hs[K1P];                 // 40064 B
  const int t = threadIdx.x;
  const int row = blockIdx.x;               // 0..511
  const int s = row >> 8, b = row & 255;

#pragma unroll
  for (int k = t * 4; k < K1P; k += 1024)
    *(f32x4*)&hs[k] = (f32x4){0.f, 0.f, 0.f, 0.f};
  __syncthreads();

  const float* mz = (s ? mz2 : mz1) + (size_t)b * PEAKS;
  const float* it = (s ? it2 : it1) + (size_t)b * PEAKS;
#pragma unroll
  for (int p = t; p < PEAKS; p += 256) {
    float m = mz[p], in = it[p];
    if (m >= 0.0f && m < 1000.0f) {
      int bin = (int)floorf(m / 0.01f);     // IEEE fp32 div+floor, matches jnp
      bin = bin < 0 ? 0 : (bin > 99999 ? 99999 : bin);
      if (bin < GROUPS * 30) {              // bins 99990..99999 dropped by ref
        int g = bin / 30;
        const float* w = Wg + (size_t)bin * 3;   // Wg[g][i][o] flat
        atomicAdd(&hs[g * 3 + 0], in * w[0]);
        atomicAdd(&hs[g * 3 + 1], in * w[1]);
        atomicAdd(&hs[g * 3 + 2], in * w[2]);
      }
    }
  }
  __syncthreads();

  _Float16* dst = h16 + (size_t)row * K1P;
  for (int k0 = t * 8; k0 < K1P; k0 += 2048) {
    half8 v;
#pragma unroll
    for (int j = 0; j < 8; ++j) {
      int k = k0 + j;
      float x = hs[k] + (k < BINNER_OUT ? bg[k] : 0.f);
      v[j] = (_Float16)x;
    }
    *(half8*)(dst + k0) = v;
  }
}

// ---- weight transpose+convert: out[n*Kpad + k] = fp16(W[k*N + n]) ---------
__global__ void transp_cvt(const float* __restrict__ W, int K, int N, int Kpad,
                           _Float16* __restrict__ out) {
  __shared__ float tile[32][33];
  int k0 = blockIdx.x * 32, n0 = blockIdx.y * 32;
  int tx = threadIdx.x & 31, ty = threadIdx.x >> 5;   // ty 0..7
#pragma unroll
  for (int i = 0; i < 4; ++i) {
    int r = ty + i * 8;
    int k = k0 + r, n = n0 + tx;
    tile[r][tx] = (k < K && n < N) ? W[(size_t)k * N + n] : 0.f;
  }
  __syncthreads();
#pragma unroll
  for (int i = 0; i < 4; ++i) {
    int r = ty + i * 8;
    out[(size_t)(n0 + r) * Kpad + (k0 + tx)] = (_Float16)tile[tx][r];
  }
}

// ---- split-K fp16 MFMA GEMM, m97 structure --------------------------------
// part[z] = A[M,K] * Bt[N,K]^T on a 128x128 tile, BK=32, 4 waves of 64x64
// (4x4 16x16 fragments), global_load_lds(16B) staging, 2-barrier K-loop.
__global__ __launch_bounds__(256) void gemm_sk(
    const _Float16* __restrict__ A, int lda,
    const _Float16* __restrict__ Bt, int ldb,
    float* __restrict__ part, int M, int Npad, int ksteps_total, int kspc) {
  __shared__ __align__(16) _Float16 As[128 * 32];   // 8 KB
  __shared__ __align__(16) _Float16 Bs[128 * 32];   // 8 KB

  const int t  = threadIdx.x;
  const int m0 = blockIdx.y * 128;
  const int n0 = blockIdx.x * 128;
  const int z  = blockIdx.z;
  int s0 = z * kspc;
  int s1 = s0 + kspc; if (s1 > ksteps_total) s1 = ksteps_total;

  const int lane = t & 63, wid = t >> 6;
  const int wr = wid >> 1, wc = wid & 1;            // 2x2 wave grid
  const int r16 = lane & 15, kh = lane >> 4;

  // staging: per wave, insts j=0,1 cover LDS [(j*4+wid)*1024 B, +1024B)
  // lane l -> tile row (j*64 + wid*16 + l/4), k = (l&3)*8
  const int srow = wid * 16 + (lane >> 2);
  const int sk   = (lane & 3) * 8;
  const _Float16* Ag = A  + (size_t)(m0 + srow) * lda + sk;
  const _Float16* Bg = Bt + (size_t)(n0 + srow) * ldb + sk;
  _Float16* AsW = &As[wid * 512];
  _Float16* BsW = &Bs[wid * 512];

  f32x4 acc[4][4] = {};

  for (int s = s0; s < s1; ++s) {
    const size_t koff = (size_t)s * 32;
    __syncthreads();
    gl_lds16(Ag + koff,                 AsW);
    gl_lds16(Ag + (size_t)64 * lda + koff, AsW + 2048);
    gl_lds16(Bg + koff,                 BsW);
    gl_lds16(Bg + (size_t)64 * ldb + koff, BsW + 2048);
    __syncthreads();                                // drains vmcnt+lgkm

    half8 af[4], bf[4];
#pragma unroll
    for (int mi = 0; mi < 4; ++mi)
      af[mi] = *(const half8*)&As[(wr * 64 + mi * 16 + r16) * 32 + kh * 8];
#pragma unroll
    for (int ni = 0; ni < 4; ++ni)
      bf[ni] = *(const half8*)&Bs[(wc * 64 + ni * 16 + r16) * 32 + kh * 8];
#pragma unroll
    for (int mi = 0; mi < 4; ++mi)
#pragma unroll
      for (int ni = 0; ni < 4; ++ni)
        acc[mi][ni] = __builtin_amdgcn_mfma_f32_16x16x32_f16(
            af[mi], bf[ni], acc[mi][ni], 0, 0, 0);
  }

  float* P = part + (size_t)z * M * Npad;
#pragma unroll
  for (int mi = 0; mi < 4; ++mi)
#pragma unroll
    for (int ni = 0; ni < 4; ++ni) {
      int row = m0 + wr * 64 + mi * 16 + kh * 4;    // C/D: row=(l>>4)*4+rr
      int col = n0 + wc * 64 + ni * 16 + r16;       //      col=l&15
#pragma unroll
      for (int rr = 0; rr < 4; ++rr)
        P[(size_t)(row + rr) * Npad + col] = acc[mi][ni][rr];
    }
}

// ---- combine split-K partials + bias (+relu), emit fp16 or fp32 ----------
__global__ void combine_sk(const float* __restrict__ part, int SK, int M, int Npad,
                           const float* __restrict__ bias, int Nreal, int relu,
                           _Float16* __restrict__ o16, float* __restrict__ o32) {
  int idx = blockIdx.x * 256 + threadIdx.x;
  int total = M * Npad;
  if (idx >= total) return;
  int n = idx & (Npad - 1);  // Npad is a power of two
  float s = 0.f;
  for (int zz = 0; zz < SK; ++zz) s += part[(size_t)zz * total + idx];
  s += (n < Nreal) ? bias[n] : 0.f;
  if (relu) s = fmaxf(s, 0.f);
  if (o16) o16[idx] = (_Float16)s;
  else     o32[idx] = s;
}

// ---- cosine similarity ----------------------------------------------------
__global__ void cosine_kernel(const float* __restrict__ E, float* __restrict__ out) {
  int b = blockIdx.x;
  const float* e1 = E + (size_t)b * NOP;
  const float* e2 = E + (size_t)(b + BATCH) * NOP;
  int t = threadIdx.x;
  float d = 0.f, s1 = 0.f, s2 = 0.f;
  for (int c = t; c < NOP; c += 256) {
    float a = e1[c], bb = e2[c];
    d += a * bb; s1 += a * a; s2 += bb * bb;
  }
  for (int off = 32; off > 0; off >>= 1) {
    d  += __shfl_down(d, off, 64);
    s1 += __shfl_down(s1, off, 64);
    s2 += __shfl_down(s2, off, 64);
  }
  __shared__ float rd[4], r1[4], r2[4];
  int wid = t >> 6, lane = t & 63;
  if (lane == 0) { rd[wid] = d; r1[wid] = s1; r2[wid] = s2; }
  __syncthreads();
  if (t == 0) {
    float D  = rd[0] + rd[1] + rd[2] + rd[3];
    float S1 = r1[0] + r1[1] + r1[2] + r1[3];
    float S2 = r2[0] + r2[1] + r2[2] + r2[3];
    float n1 = fmaxf(sqrtf(S1), 1e-6f);
    float n2 = fmaxf(sqrtf(S2), 1e-6f);
    out[b] = D / (n1 * n2);
  }
}

extern "C" void kernel_launch(void* const* d_in, const int* in_sizes, int n_in,
                              void* d_out, int out_size, void* d_ws, size_t ws_size,
                              hipStream_t stream) {
  const float* mz1 = (const float*)d_in[0];
  const float* it1 = (const float*)d_in[1];
  const float* mz2 = (const float*)d_in[2];
  const float* it2 = (const float*)d_in[3];
  const float* Wg  = (const float*)d_in[4];
  const float* bg  = (const float*)d_in[5];
  const float* W1  = (const float*)d_in[6];
  const float* b1  = (const float*)d_in[7];
  const float* W2  = (const float*)d_in[8];
  const float* b2  = (const float*)d_in[9];
  const float* W3  = (const float*)d_in[10];
  const float* b3  = (const float*)d_in[11];
  const float* Wo  = (const float*)d_in[12];
  const float* bo  = (const float*)d_in[13];
  float* out = (float*)d_out;

  char* ws = (char*)d_ws;
  size_t off = 0;
  auto take = [&](size_t bytes) {
    size_t o = off; off += (bytes + 255) & ~(size_t)255; return o;
  };
  float*    part = (float*)   (ws + take((size_t)8 * ROWS * NP * 4));  // 16MB
  _Float16* h16  = (_Float16*)(ws + take((size_t)ROWS * K1P * 2));
  _Float16* W1t  = (_Float16*)(ws + take((size_t)NP * K1P * 2));
  _Float16* W2t  = (_Float16*)(ws + take((size_t)NP * NP * 2));
  _Float16* W3t  = (_Float16*)(ws + take((size_t)NP * NP * 2));
  _Float16* Wot  = (_Float16*)(ws + take((size_t)NOP * NP * 2));
  _Float16* y1   = (_Float16*)(ws + take((size_t)ROWS * NP * 2));
  _Float16* y2   = (_Float16*)(ws + take((size_t)ROWS * NP * 2));
  _Float16* y3   = (_Float16*)(ws + take((size_t)ROWS * NP * 2));
  float*    E    = (float*)   (ws + take((size_t)ROWS * NOP * 4));

  // 1) binning + grouped linear + bias + fp16 conversion, fused per row
  fused_bin<<<ROWS, 256, 0, stream>>>(mz1, it1, mz2, it2, Wg, bg, h16);

  // 2) weights -> fp16, transposed to [N][Kpad], zero-padded
  transp_cvt<<<dim3(K1P / 32, NP / 32),  256, 0, stream>>>(W1, K1,   1000, K1P, W1t);
  transp_cvt<<<dim3(NP / 32,  NP / 32),  256, 0, stream>>>(W2, 1000, 1000, NP,  W2t);
  transp_cvt<<<dim3(NP / 32,  NP / 32),  256, 0, stream>>>(W3, 1000, 1000, NP,  W3t);
  transp_cvt<<<dim3(NP / 32,  NOP / 32), 256, 0, stream>>>(Wo, 1000, 500,  NP,  Wot);

  // 3) MLP: L1 (K=10016, SK=8), L2/L3 (K=1024, SK=4), Lo (N=512, SK=8)
  gemm_sk<<<dim3(NP / 128, ROWS / 128, 8), 256, 0, stream>>>(
      h16, K1P, W1t, K1P, part, ROWS, NP, K1P / 32, 40);
  combine_sk<<<(ROWS * NP) / 256, 256, 0, stream>>>(part, 8, ROWS, NP, b1, 1000, 1, y1, nullptr);

  gemm_sk<<<dim3(NP / 128, ROWS / 128, 4), 256, 0, stream>>>(
      y1, NP, W2t, NP, part, ROWS, NP, NP / 32, 8);
  combine_sk<<<(ROWS * NP) / 256, 256, 0, stream>>>(part, 4, ROWS, NP, b2, 1000, 1, y2, nullptr);

  gemm_sk<<<dim3(NP / 128, ROWS / 128, 4), 256, 0, stream>>>(
      y2, NP, W3t, NP, part, ROWS, NP, NP / 32, 8);
  combine_sk<<<(ROWS * NP) / 256, 256, 0, stream>>>(part, 4, ROWS, NP, b3, 1000, 1, y3, nullptr);

  gemm_sk<<<dim3(NOP / 128, ROWS / 128, 8), 256, 0, stream>>>(
      y3, NP, Wot, NP, part, ROWS, NOP, NP / 32, 4);
  combine_sk<<<(ROWS * NOP) / 256, 256, 0, stream>>>(part, 8, ROWS, NOP, bo, 500, 0, nullptr, E);

  // 4) cosine similarity
  cosine_kernel<<<BATCH, 256, 0, stream>>>(E, out);
}

// Round 4
// 124.906 us; speedup vs baseline: 1.0890x; 1.0890x over previous
//
#include <hip/hip_runtime.h>
#include <hip/hip_fp16.h>

using half8  = __attribute__((ext_vector_type(8))) _Float16;
using f32x4  = __attribute__((ext_vector_type(4))) float;

#define GROUPS      3333
#define BINNER_OUT  9999
#define BATCH       256
#define ROWS        512          // 2 spectra x 256
#define PEAKS       512
#define K1          9999
#define K1P         10016        // K1 padded to mult of 32 (313 * 32)
#define NP          1024         // hidden 1000 padded
#define NOP         512          // out 500 padded

// ---- async global->LDS, 16B per lane (dest = uniform base + lane*16) ------
__device__ __forceinline__ void gl_lds16(const void* g, void* l) {
  __builtin_amdgcn_global_load_lds(
      (const __attribute__((address_space(1))) void*)g,
      (__attribute__((address_space(3))) void*)l, 16, 0, 0);
}

// ---- fused binning: per-row LDS accumulator -------------------------------
__global__ __launch_bounds__(256) void fused_bin(
    const float* __restrict__ mz1, const float* __restrict__ it1,
    const float* __restrict__ mz2, const float* __restrict__ it2,
    const float* __restrict__ Wg,  const float* __restrict__ bg,
    _Float16* __restrict__ h16) {
  __shared__ float hs[K1P];                 // 40064 B
  const int t = threadIdx.x;
  const int row = blockIdx.x;               // 0..511
  const int s = row >> 8, b = row & 255;

#pragma unroll
  for (int k = t * 4; k < K1P; k += 1024)
    *(f32x4*)&hs[k] = (f32x4){0.f, 0.f, 0.f, 0.f};
  __syncthreads();

  const float* mz = (s ? mz2 : mz1) + (size_t)b * PEAKS;
  const float* it = (s ? it2 : it1) + (size_t)b * PEAKS;
#pragma unroll
  for (int p = t; p < PEAKS; p += 256) {
    float m = mz[p], in = it[p];
    if (m >= 0.0f && m < 1000.0f) {
      int bin = (int)floorf(m / 0.01f);     // IEEE fp32 div+floor, matches jnp
      bin = bin < 0 ? 0 : (bin > 99999 ? 99999 : bin);
      if (bin < GROUPS * 30) {              // bins 99990..99999 dropped by ref
        int g = bin / 30;
        const float* w = Wg + (size_t)bin * 3;   // Wg[g][i][o] flat
        atomicAdd(&hs[g * 3 + 0], in * w[0]);
        atomicAdd(&hs[g * 3 + 1], in * w[1]);
        atomicAdd(&hs[g * 3 + 2], in * w[2]);
      }
    }
  }
  __syncthreads();

  _Float16* dst = h16 + (size_t)row * K1P;
  for (int k0 = t * 8; k0 < K1P; k0 += 2048) {
    half8 v;
#pragma unroll
    for (int j = 0; j < 8; ++j) {
      int k = k0 + j;
      float x = hs[k] + (k < BINNER_OUT ? bg[k] : 0.f);
      v[j] = (_Float16)x;
    }
    *(half8*)(dst + k0) = v;
  }
}

// ---- weight transpose+convert: out[n*Kpad + k] = fp16(W[k*N + n]) ---------
__global__ void transp_cvt(const float* __restrict__ W, int K, int N, int Kpad,
                           _Float16* __restrict__ out) {
  __shared__ float tile[32][33];
  int k0 = blockIdx.x * 32, n0 = blockIdx.y * 32;
  int tx = threadIdx.x & 31, ty = threadIdx.x >> 5;   // ty 0..7
#pragma unroll
  for (int i = 0; i < 4; ++i) {
    int r = ty + i * 8;
    int k = k0 + r, n = n0 + tx;
    tile[r][tx] = (k < K && n < N) ? W[(size_t)k * N + n] : 0.f;
  }
  __syncthreads();
#pragma unroll
  for (int i = 0; i < 4; ++i) {
    int r = ty + i * 8;
    out[(size_t)(n0 + r) * Kpad + (k0 + tx)] = (_Float16)tile[tx][r];
  }
}

// ---- split-K fp16 MFMA GEMM, dbuf-pipelined -------------------------------
// part[z] = A[M,K] * Bt[N,K]^T. Tile 64x128, BK=32, 4 waves of 32x64.
// global_load_lds(16B) staging, 2-deep double buffer, ONE barrier per K-step.
// LDS k-chunks XOR-swizzled (writer: pre-swizzled global src; reader: kh XOR)
// so ds_read_b128 is 2-way (free) instead of 8-way conflicted.
template <bool SWZ>
__global__ __launch_bounds__(256) void gemm_sk(
    const _Float16* __restrict__ A, int lda,
    const _Float16* __restrict__ Bt, int ldb,
    float* __restrict__ part, int M, int Npad, int ksteps_total, int kspc) {
  __shared__ __align__(16) _Float16 As[2 * 2048];   //  8 KB: 2 x 64x32
  __shared__ __align__(16) _Float16 Bs[2 * 4096];   // 16 KB: 2 x 128x32

  int bx, by, bz;
  if (SWZ) {   // grid must be 8x8x8 linearized: each XCD owns a 2x x 4y region
    int bid = blockIdx.x;
    int xcd = bid & 7, i = bid >> 3;
    bz = i >> 3;
    int j = i & 7;
    bx = (xcd & 3) * 2 + (j & 1);
    by = (xcd >> 2) * 4 + (j >> 1);
  } else {
    bx = blockIdx.x; by = blockIdx.y; bz = blockIdx.z;
  }

  const int t  = threadIdx.x;
  const int m0 = by * 64;
  const int n0 = bx * 128;
  int s0 = bz * kspc;
  int s1 = s0 + kspc; if (s1 > ksteps_total) s1 = ksteps_total;

  const int lane = t & 63, wid = t >> 6;
  const int wr = wid >> 1, wc = wid & 1;            // 2x2 waves, 32x64 each
  const int r16 = lane & 15, kh = lane >> 4;
  const int khs = (kh ^ ((r16 >> 1) & 3)) * 8;      // swizzled k-chunk (read)

  // staging: lane l -> LDS row wid*16 + l/4, k-chunk (l&3); global source
  // k-chunk pre-swizzled by ^((l>>3)&3) == ^((row>>1)&3)
  const int srow = wid * 16 + (lane >> 2);
  const int skx  = (((lane & 3) ^ ((lane >> 3) & 3)) * 8);
  const _Float16* Ag  = A  + (size_t)(m0 + srow) * lda + skx;
  const _Float16* Bg0 = Bt + (size_t)(n0 + srow) * ldb + skx;
  const _Float16* Bg1 = Bg0 + (size_t)64 * ldb;
  _Float16* AsW = As + wid * 512;
  _Float16* BsW = Bs + wid * 512;

  f32x4 acc[2][4] = {};

  // prologue: stage step s0 into buffer 0
  {
    const size_t ko = (size_t)s0 * 32;
    gl_lds16(Ag  + ko, AsW);
    gl_lds16(Bg0 + ko, BsW);
    gl_lds16(Bg1 + ko, BsW + 2048);
  }
  __syncthreads();

  for (int s = s0; s < s1; ++s) {
    const int cur = (s - s0) & 1;
    if (s + 1 < s1) {                       // prefetch next into other buffer
      const int nxt = cur ^ 1;
      const size_t ko = (size_t)(s + 1) * 32;
      gl_lds16(Ag  + ko, AsW + nxt * 2048);
      gl_lds16(Bg0 + ko, BsW + nxt * 4096);
      gl_lds16(Bg1 + ko, BsW + nxt * 4096 + 2048);
    }
    const _Float16* Ab = As + cur * 2048;
    const _Float16* Bb = Bs + cur * 4096;
    half8 af[2], bf[4];
#pragma unroll
    for (int mi = 0; mi < 2; ++mi)
      af[mi] = *(const half8*)&Ab[(wr * 32 + mi * 16 + r16) * 32 + khs];
#pragma unroll
    for (int ni = 0; ni < 4; ++ni)
      bf[ni] = *(const half8*)&Bb[(wc * 64 + ni * 16 + r16) * 32 + khs];
#pragma unroll
    for (int mi = 0; mi < 2; ++mi)
#pragma unroll
      for (int ni = 0; ni < 4; ++ni)
        acc[mi][ni] = __builtin_amdgcn_mfma_f32_16x16x32_f16(
            af[mi], bf[ni], acc[mi][ni], 0, 0, 0);
    __syncthreads();   // vmcnt(0)+lgkmcnt(0)+barrier: next buffer ready
  }

  float* P = part + (size_t)bz * M * Npad;
#pragma unroll
  for (int mi = 0; mi < 2; ++mi)
#pragma unroll
    for (int ni = 0; ni < 4; ++ni) {
      int row = m0 + wr * 32 + mi * 16 + kh * 4;    // C/D: row=(l>>4)*4+rr
      int col = n0 + wc * 64 + ni * 16 + r16;       //      col=l&15
#pragma unroll
      for (int rr = 0; rr < 4; ++rr)
        P[(size_t)(row + rr) * Npad + col] = acc[mi][ni][rr];
    }
}

// ---- combine split-K partials + bias (+relu), emit fp16 or fp32 ----------
__global__ void combine_sk(const float* __restrict__ part, int SK, int M, int Npad,
                           const float* __restrict__ bias, int Nreal, int relu,
                           _Float16* __restrict__ o16, float* __restrict__ o32) {
  int idx = blockIdx.x * 256 + threadIdx.x;
  int total = M * Npad;
  if (idx >= total) return;
  int n = idx & (Npad - 1);  // Npad is a power of two
  float s = 0.f;
  for (int zz = 0; zz < SK; ++zz) s += part[(size_t)zz * total + idx];
  s += (n < Nreal) ? bias[n] : 0.f;
  if (relu) s = fmaxf(s, 0.f);
  if (o16) o16[idx] = (_Float16)s;
  else     o32[idx] = s;
}

// ---- cosine similarity ----------------------------------------------------
__global__ void cosine_kernel(const float* __restrict__ E, float* __restrict__ out) {
  int b = blockIdx.x;
  const float* e1 = E + (size_t)b * NOP;
  const float* e2 = E + (size_t)(b + BATCH) * NOP;
  int t = threadIdx.x;
  float d = 0.f, s1 = 0.f, s2 = 0.f;
  for (int c = t; c < NOP; c += 256) {
    float a = e1[c], bb = e2[c];
    d += a * bb; s1 += a * a; s2 += bb * bb;
  }
  for (int off = 32; off > 0; off >>= 1) {
    d  += __shfl_down(d, off, 64);
    s1 += __shfl_down(s1, off, 64);
    s2 += __shfl_down(s2, off, 64);
  }
  __shared__ float rd[4], r1[4], r2[4];
  int wid = t >> 6, lane = t & 63;
  if (lane == 0) { rd[wid] = d; r1[wid] = s1; r2[wid] = s2; }
  __syncthreads();
  if (t == 0) {
    float D  = rd[0] + rd[1] + rd[2] + rd[3];
    float S1 = r1[0] + r1[1] + r1[2] + r1[3];
    float S2 = r2[0] + r2[1] + r2[2] + r2[3];
    float n1 = fmaxf(sqrtf(S1), 1e-6f);
    float n2 = fmaxf(sqrtf(S2), 1e-6f);
    out[b] = D / (n1 * n2);
  }
}

extern "C" void kernel_launch(void* const* d_in, const int* in_sizes, int n_in,
                              void* d_out, int out_size, void* d_ws, size_t ws_size,
                              hipStream_t stream) {
  const float* mz1 = (const float*)d_in[0];
  const float* it1 = (const float*)d_in[1];
  const float* mz2 = (const float*)d_in[2];
  const float* it2 = (const float*)d_in[3];
  const float* Wg  = (const float*)d_in[4];
  const float* bg  = (const float*)d_in[5];
  const float* W1  = (const float*)d_in[6];
  const float* b1  = (const float*)d_in[7];
  const float* W2  = (const float*)d_in[8];
  const float* b2  = (const float*)d_in[9];
  const float* W3  = (const float*)d_in[10];
  const float* b3  = (const float*)d_in[11];
  const float* Wo  = (const float*)d_in[12];
  const float* bo  = (const float*)d_in[13];
  float* out = (float*)d_out;

  char* ws = (char*)d_ws;
  size_t off = 0;
  auto take = [&](size_t bytes) {
    size_t o = off; off += (bytes + 255) & ~(size_t)255; return o;
  };
  float*    part = (float*)   (ws + take((size_t)8 * ROWS * NP * 4));  // 16MB
  _Float16* h16  = (_Float16*)(ws + take((size_t)ROWS * K1P * 2));
  _Float16* W1t  = (_Float16*)(ws + take((size_t)NP * K1P * 2));
  _Float16* W2t  = (_Float16*)(ws + take((size_t)NP * NP * 2));
  _Float16* W3t  = (_Float16*)(ws + take((size_t)NP * NP * 2));
  _Float16* Wot  = (_Float16*)(ws + take((size_t)NOP * NP * 2));
  _Float16* y1   = (_Float16*)(ws + take((size_t)ROWS * NP * 2));
  _Float16* y2   = (_Float16*)(ws + take((size_t)ROWS * NP * 2));
  _Float16* y3   = (_Float16*)(ws + take((size_t)ROWS * NP * 2));
  float*    E    = (float*)   (ws + take((size_t)ROWS * NOP * 4));

  // 1) binning + grouped linear + bias + fp16 conversion, fused per row
  fused_bin<<<ROWS, 256, 0, stream>>>(mz1, it1, mz2, it2, Wg, bg, h16);

  // 2) weights -> fp16, transposed to [N][Kpad], zero-padded
  transp_cvt<<<dim3(K1P / 32, NP / 32),  256, 0, stream>>>(W1, K1,   1000, K1P, W1t);
  transp_cvt<<<dim3(NP / 32,  NP / 32),  256, 0, stream>>>(W2, 1000, 1000, NP,  W2t);
  transp_cvt<<<dim3(NP / 32,  NP / 32),  256, 0, stream>>>(W3, 1000, 1000, NP,  W3t);
  transp_cvt<<<dim3(NP / 32,  NOP / 32), 256, 0, stream>>>(Wo, 1000, 500,  NP,  Wot);

  // 3) MLP. All grids 512 blocks (2 blocks/CU). L1: SK=8 over 313 K-steps.
  gemm_sk<true><<<512, 256, 0, stream>>>(
      h16, K1P, W1t, K1P, part, ROWS, NP, K1P / 32, 40);
  combine_sk<<<(ROWS * NP) / 256, 256, 0, stream>>>(part, 8, ROWS, NP, b1, 1000, 1, y1, nullptr);

  gemm_sk<true><<<512, 256, 0, stream>>>(
      y1, NP, W2t, NP, part, ROWS, NP, NP / 32, 4);
  combine_sk<<<(ROWS * NP) / 256, 256, 0, stream>>>(part, 8, ROWS, NP, b2, 1000, 1, y2, nullptr);

  gemm_sk<true><<<512, 256, 0, stream>>>(
      y2, NP, W3t, NP, part, ROWS, NP, NP / 32, 4);
  combine_sk<<<(ROWS * NP) / 256, 256, 0, stream>>>(part, 8, ROWS, NP, b3, 1000, 1, y3, nullptr);

  gemm_sk<false><<<dim3(NOP / 128, ROWS / 64, 8), 256, 0, stream>>>(
      y3, NP, Wot, NP, part, ROWS, NOP, NP / 32, 4);
  combine_sk<<<(ROWS * NOP) / 256, 256, 0, stream>>>(part, 8, ROWS, NOP, bo, 500, 0, nullptr, E);

  // 4) cosine similarity
  cosine_kernel<<<BATCH, 256, 0, stream>>>(E, out);
}

// Round 5
// 110.397 us; speedup vs baseline: 1.2321x; 1.1314x over previous
//
#include <hip/hip_runtime.h>
#include <hip/hip_fp16.h>

using half8  = __attribute__((ext_vector_type(8))) _Float16;
using f32x4  = __attribute__((ext_vector_type(4))) float;

#define GROUPS      3333
#define BINNER_OUT  9999
#define BATCH       256
#define ROWS        512          // 2 spectra x 256
#define PEAKS       512
#define K1          9999
#define K1P         10048        // padded to mult of 64 (157*64)
#define NP          1024         // hidden 1000 padded
#define NOP         512          // out 500 padded

// ---- async global->LDS, 16B per lane (dest = uniform base + lane*16) ------
__device__ __forceinline__ void gl_lds16(const void* g, void* l) {
  __builtin_amdgcn_global_load_lds(
      (const __attribute__((address_space(1))) void*)g,
      (__attribute__((address_space(3))) void*)l, 16, 0, 0);
}

// ---- prep: fused binning (blocks [0,512)) + weight transposes (rest) ------
// fused_bin: per-row LDS accumulator -> h16 row (+bg, fp16, zero-pad K1P).
// transp: out[n*Kpad + k] = fp16(W[k*N + n]), zero-padded.
__global__ __launch_bounds__(256) void prep(
    const float* __restrict__ mz1, const float* __restrict__ it1,
    const float* __restrict__ mz2, const float* __restrict__ it2,
    const float* __restrict__ Wg,  const float* __restrict__ bg,
    _Float16* __restrict__ h16,
    const float* __restrict__ W1, _Float16* __restrict__ W1t,
    const float* __restrict__ W2, _Float16* __restrict__ W2t,
    const float* __restrict__ W3, _Float16* __restrict__ W3t,
    const float* __restrict__ Wo, _Float16* __restrict__ Wot) {
  __shared__ float sh[K1P];                 // 40192 B (transp uses a corner)
  const int t = threadIdx.x;
  const int blk = blockIdx.x;

  if (blk < ROWS) {
    // ---------------- binning + grouped linear ----------------
    const int s = blk >> 8, b = blk & 255;
    for (int k = t * 4; k < K1P; k += 1024)
      *(f32x4*)&sh[k] = (f32x4){0.f, 0.f, 0.f, 0.f};
    __syncthreads();

    const float* mz = (s ? mz2 : mz1) + (size_t)b * PEAKS;
    const float* it = (s ? it2 : it1) + (size_t)b * PEAKS;
#pragma unroll
    for (int p = t; p < PEAKS; p += 256) {
      float m = mz[p], in = it[p];
      if (m >= 0.0f && m < 1000.0f) {
        int bin = (int)floorf(m / 0.01f);   // IEEE fp32 div+floor, matches jnp
        bin = bin < 0 ? 0 : (bin > 99999 ? 99999 : bin);
        if (bin < GROUPS * 30) {            // bins 99990..99999 dropped by ref
          int g = bin / 30;
          const float* w = Wg + (size_t)bin * 3;
          atomicAdd(&sh[g * 3 + 0], in * w[0]);
          atomicAdd(&sh[g * 3 + 1], in * w[1]);
          atomicAdd(&sh[g * 3 + 2], in * w[2]);
        }
      }
    }
    __syncthreads();

    _Float16* dst = h16 + (size_t)blk * K1P;
    for (int k0 = t * 8; k0 < K1P; k0 += 2048) {
      half8 v;
#pragma unroll
      for (int j = 0; j < 8; ++j) {
        int k = k0 + j;
        float x = sh[k] + (k < BINNER_OUT ? bg[k] : 0.f);
        v[j] = (_Float16)x;
      }
      *(half8*)(dst + k0) = v;
    }
  } else {
    // ---------------- weight transpose+convert ----------------
    int bid = blk - ROWS;
    const float* W; _Float16* outp; int K, N, Kpad, ik, in;
    if (bid < 10048)      { W = W1; outp = W1t; K = K1;   N = 1000; Kpad = K1P;
                            ik = bid % 314; in = bid / 314; }
    else if (bid < 11072) { bid -= 10048; W = W2; outp = W2t; K = 1000; N = 1000;
                            Kpad = NP; ik = bid & 31; in = bid >> 5; }
    else if (bid < 12096) { bid -= 11072; W = W3; outp = W3t; K = 1000; N = 1000;
                            Kpad = NP; ik = bid & 31; in = bid >> 5; }
    else                  { bid -= 12096; W = Wo; outp = Wot; K = 1000; N = 500;
                            Kpad = NP; ik = bid & 31; in = bid >> 5; }
    float (*tile)[33] = (float(*)[33])sh;
    int k0 = ik * 32, n0 = in * 32;
    int tx = t & 31, ty = t >> 5;           // ty 0..7
#pragma unroll
    for (int i = 0; i < 4; ++i) {
      int r = ty + i * 8;
      int k = k0 + r, n = n0 + tx;
      tile[r][tx] = (k < K && n < N) ? W[(size_t)k * N + n] : 0.f;
    }
    __syncthreads();
#pragma unroll
    for (int i = 0; i < 4; ++i) {
      int r = ty + i * 8;
      outp[(size_t)(n0 + r) * Kpad + (k0 + tx)] = (_Float16)tile[tx][r];
    }
  }
}

// ---- split-K fp16 MFMA GEMM, 3-deep counted-vmcnt pipeline ----------------
// part[z] = A[M,K] * Bt[N,K]^T. Tile 64x128, BK=64, 4 waves of 32x64.
// global_load_lds(16B) staging into 3 LDS buffers; raw s_barrier + literal
// s_waitcnt vmcnt(N) keep 2 K-steps of loads in flight (never drain to 0).
// LDS rows are 128B; k-chunks XOR-swizzled (pre-swizzled global source,
// matching XOR on ds_read) -> 2 lanes/bank (free) instead of 16-way.
template <bool SWZ>
__global__ __launch_bounds__(256) void gemm_sk(
    const _Float16* __restrict__ A, int lda,
    const _Float16* __restrict__ Bt, int ldb,
    float* __restrict__ part, int M, int Npad, int ksteps_total, int kspc) {
  __shared__ __align__(16) _Float16 As[3 * 4096];   // 3 x 64x64  = 24 KB
  __shared__ __align__(16) _Float16 Bs[3 * 8192];   // 3 x 128x64 = 48 KB

  int bx, by, bz;
  if (SWZ) {   // 512 blocks = 8x8x8; each XCD owns a 2(bx) x 4(by) region
    int bid = blockIdx.x;
    int xcd = bid & 7, i = bid >> 3;
    bz = i >> 3;
    int j = i & 7;
    bx = (xcd & 3) * 2 + (j & 1);
    by = (xcd >> 2) * 4 + (j >> 1);
  } else {
    bx = blockIdx.x; by = blockIdx.y; bz = blockIdx.z;
  }

  const int t = threadIdx.x, lane = t & 63, wid = t >> 6;
  const int m0 = by * 64, n0 = bx * 128;
  const int s0 = bz * kspc;
  const int s1 = min(s0 + kspc, ksteps_total);

  const int wr = wid >> 1, wc = wid & 1;            // 2x2 waves, 32x64 each
  const int r16 = lane & 15, kh = lane >> 4;

  // staging: lane l covers row base+(l>>3), global k-chunk ((l&7)^(l>>3))*8
  const int lr  = lane >> 3;
  const int lkc = ((lane & 7) ^ lr) * 8;
  const _Float16* AgL = A  + (size_t)(m0 + wid * 16 + lr) * lda + lkc;
  const _Float16* BgL = Bt + (size_t)(n0 + wid * 32 + lr) * ldb + lkc;

  f32x4 acc[2][4] = {};

  auto STAGE = [&](int s, int buf) {
    const size_t ko = (size_t)s * 64;
    _Float16* ab = As + buf * 4096 + wid * 1024;
    _Float16* bb = Bs + buf * 8192 + wid * 2048;
    gl_lds16(AgL + ko,                     ab);
    gl_lds16(AgL + ko + (size_t) 8 * lda,  ab + 512);
    gl_lds16(BgL + ko,                     bb);
    gl_lds16(BgL + ko + (size_t) 8 * ldb,  bb + 512);
    gl_lds16(BgL + ko + (size_t)16 * ldb,  bb + 1024);
    gl_lds16(BgL + ko + (size_t)24 * ldb,  bb + 1536);
  };

  if (s0 < s1)     STAGE(s0, 0);
  if (s0 + 1 < s1) STAGE(s0 + 1, 1);

  int cur = 0;
  for (int s = s0; s < s1; ++s) {
    __builtin_amdgcn_s_barrier();           // prev step's readers are done
    const bool more2 = (s + 2 < s1), more1 = (s + 1 < s1);
    if (more2) STAGE(s + 2, cur == 0 ? 2 : (cur == 1 ? 0 : 1));
    if (more2)      asm volatile("s_waitcnt vmcnt(12)" ::: "memory");
    else if (more1) asm volatile("s_waitcnt vmcnt(6)"  ::: "memory");
    else            asm volatile("s_waitcnt vmcnt(0)"  ::: "memory");
    __builtin_amdgcn_s_barrier();           // ALL waves' stage(s) complete

    const char* Ab = (const char*)(As + cur * 4096);
    const char* Bb = (const char*)(Bs + cur * 8192);
    half8 af[2][2], bf[4][2];
#pragma unroll
    for (int kc = 0; kc < 2; ++kc) {
#pragma unroll
      for (int mi = 0; mi < 2; ++mi) {
        int row = wr * 32 + mi * 16 + r16;
        af[mi][kc] = *(const half8*)(Ab + row * 128 +
                     (((kc << 6) + (kh << 4)) ^ ((row & 7) << 4)));
      }
#pragma unroll
      for (int ni = 0; ni < 4; ++ni) {
        int row = wc * 64 + ni * 16 + r16;
        bf[ni][kc] = *(const half8*)(Bb + row * 128 +
                     (((kc << 6) + (kh << 4)) ^ ((row & 7) << 4)));
      }
    }
#pragma unroll
    for (int kc = 0; kc < 2; ++kc)
#pragma unroll
      for (int mi = 0; mi < 2; ++mi)
#pragma unroll
        for (int ni = 0; ni < 4; ++ni)
          acc[mi][ni] = __builtin_amdgcn_mfma_f32_16x16x32_f16(
              af[mi][kc], bf[ni][kc], acc[mi][ni], 0, 0, 0);
    cur = cur == 2 ? 0 : cur + 1;
  }

  float* P = part + (size_t)bz * M * Npad;
#pragma unroll
  for (int mi = 0; mi < 2; ++mi)
#pragma unroll
    for (int ni = 0; ni < 4; ++ni) {
      int row = m0 + wr * 32 + mi * 16 + kh * 4;    // C/D: row=(l>>4)*4+rr
      int col = n0 + wc * 64 + ni * 16 + r16;       //      col=l&15
#pragma unroll
      for (int rr = 0; rr < 4; ++rr)
        P[(size_t)(row + rr) * Npad + col] = acc[mi][ni][rr];
    }
}

// ---- combine split-K partials + bias + relu, emit fp16 --------------------
__global__ void combine_sk(const float* __restrict__ part, int SK, int M, int Npad,
                           const float* __restrict__ bias, int Nreal,
                           _Float16* __restrict__ o16) {
  int idx = blockIdx.x * 256 + threadIdx.x;
  int total = M * Npad;
  if (idx >= total) return;
  int n = idx & (Npad - 1);  // Npad is a power of two
  float s = 0.f;
  for (int zz = 0; zz < SK; ++zz) s += part[(size_t)zz * total + idx];
  s += (n < Nreal) ? bias[n] : 0.f;
  o16[idx] = (_Float16)fmaxf(s, 0.f);
}

// ---- final combine (split-K + bias, no relu) fused with cosine ------------
__global__ void combine_cos(const float* __restrict__ part,
                            const float* __restrict__ bo,
                            float* __restrict__ out) {
  const int b = blockIdx.x, t = threadIdx.x;
  float d = 0.f, s1 = 0.f, s2 = 0.f;
  for (int c = t; c < NOP; c += 256) {
    float e1 = 0.f, e2 = 0.f;
#pragma unroll
    for (int z = 0; z < 8; ++z) {
      e1 += part[((size_t)z * ROWS + b) * NOP + c];
      e2 += part[((size_t)z * ROWS + b + BATCH) * NOP + c];
    }
    if (c < 500) { float bb = bo[c]; e1 += bb; e2 += bb; }
    d += e1 * e2; s1 += e1 * e1; s2 += e2 * e2;
  }
  for (int off = 32; off > 0; off >>= 1) {
    d  += __shfl_down(d, off, 64);
    s1 += __shfl_down(s1, off, 64);
    s2 += __shfl_down(s2, off, 64);
  }
  __shared__ float rd[4], r1[4], r2[4];
  int wd = t >> 6, lane = t & 63;
  if (lane == 0) { rd[wd] = d; r1[wd] = s1; r2[wd] = s2; }
  __syncthreads();
  if (t == 0) {
    float D  = rd[0] + rd[1] + rd[2] + rd[3];
    float S1 = r1[0] + r1[1] + r1[2] + r1[3];
    float S2 = r2[0] + r2[1] + r2[2] + r2[3];
    float n1 = fmaxf(sqrtf(S1), 1e-6f);
    float n2 = fmaxf(sqrtf(S2), 1e-6f);
    out[b] = D / (n1 * n2);
  }
}

extern "C" void kernel_launch(void* const* d_in, const int* in_sizes, int n_in,
                              void* d_out, int out_size, void* d_ws, size_t ws_size,
                              hipStream_t stream) {
  const float* mz1 = (const float*)d_in[0];
  const float* it1 = (const float*)d_in[1];
  const float* mz2 = (const float*)d_in[2];
  const float* it2 = (const float*)d_in[3];
  const float* Wg  = (const float*)d_in[4];
  const float* bg  = (const float*)d_in[5];
  const float* W1  = (const float*)d_in[6];
  const float* b1  = (const float*)d_in[7];
  const float* W2  = (const float*)d_in[8];
  const float* b2  = (const float*)d_in[9];
  const float* W3  = (const float*)d_in[10];
  const float* b3  = (const float*)d_in[11];
  const float* Wo  = (const float*)d_in[12];
  const float* bo  = (const float*)d_in[13];
  float* out = (float*)d_out;

  char* ws = (char*)d_ws;
  size_t off = 0;
  auto take = [&](size_t bytes) {
    size_t o = off; off += (bytes + 255) & ~(size_t)255; return o;
  };
  float*    part = (float*)   (ws + take((size_t)8 * ROWS * NP * 4));  // 16MB
  _Float16* h16  = (_Float16*)(ws + take((size_t)ROWS * K1P * 2));
  _Float16* W1t  = (_Float16*)(ws + take((size_t)NP * K1P * 2));
  _Float16* W2t  = (_Float16*)(ws + take((size_t)NP * NP * 2));
  _Float16* W3t  = (_Float16*)(ws + take((size_t)NP * NP * 2));
  _Float16* Wot  = (_Float16*)(ws + take((size_t)NOP * NP * 2));
  _Float16* y1   = (_Float16*)(ws + take((size_t)ROWS * NP * 2));
  _Float16* y2   = (_Float16*)(ws + take((size_t)ROWS * NP * 2));
  _Float16* y3   = (_Float16*)(ws + take((size_t)ROWS * NP * 2));

  // 1) binning + grouped linear + all weight transposes, one dispatch
  prep<<<ROWS + 12608, 256, 0, stream>>>(mz1, it1, mz2, it2, Wg, bg, h16,
                                         W1, W1t, W2, W2t, W3, W3t, Wo, Wot);

  // 2) MLP. L1: 157 K-steps of 64, SK=8 (kspc 20); L2/L3/Lo: 16 steps, SK=8.
  gemm_sk<true><<<512, 256, 0, stream>>>(
      h16, K1P, W1t, K1P, part, ROWS, NP, K1P / 64, 20);
  combine_sk<<<(ROWS * NP) / 256, 256, 0, stream>>>(part, 8, ROWS, NP, b1, 1000, y1);

  gemm_sk<true><<<512, 256, 0, stream>>>(
      y1, NP, W2t, NP, part, ROWS, NP, NP / 64, 2);
  combine_sk<<<(ROWS * NP) / 256, 256, 0, stream>>>(part, 8, ROWS, NP, b2, 1000, y2);

  gemm_sk<true><<<512, 256, 0, stream>>>(
      y2, NP, W3t, NP, part, ROWS, NP, NP / 64, 2);
  combine_sk<<<(ROWS * NP) / 256, 256, 0, stream>>>(part, 8, ROWS, NP, b3, 1000, y3);

  gemm_sk<false><<<dim3(NOP / 128, ROWS / 64, 8), 256, 0, stream>>>(
      y3, NP, Wot, NP, part, ROWS, NOP, NP / 64, 2);

  // 3) final combine + cosine
  combine_cos<<<BATCH, 256, 0, stream>>>(part, bo, out);
}